// Round 5
// baseline (997.499 us; speedup 1.0000x reference)
//
#include <hip/hip_runtime.h>
#include <cstdint>
#include <cstddef>

typedef unsigned short u16t;
typedef __attribute__((ext_vector_type(8))) short short8;   // 8 x bf16 (4 VGPRs)
typedef __attribute__((ext_vector_type(4))) float float4v;  // MFMA C/D frag

#define NATOMS 50400
#define SSP    7
#define DIN    1008
#define KP     1024     // layer-1 K padded
#define GRP    7200     // atoms per species
#define GPAD   7296     // 57 * 128
#define H0D    256
#define H1D    192
#define H2D    160
#define GBSM   28       // bsm per pass (2 passes over 56)

// ---- workspace byte offsets (all 16B aligned) ----
#define OFF_CNT   0ull
#define OFF_SRC   256ull                 // 7*7296*4 = 204288
#define OFF_X     204544ull              // 7*7296*1024*2 = 104595456
#define OFF_W0T   104800000ull           // 56*256*1024*2 = 29360128
#define OFF_W1T   134160128ull           // 56*192*256*2  = 5505024
#define OFF_W2T   139665152ull           // 56*160*192*2  = 3440640
#define OFF_H0    143105792ull           // 28*7296*256*2 = 104595456 -> end 247701248

__device__ __forceinline__ u16t f2bf(float f) {
    union { float f; unsigned u; } x; x.f = f;
    unsigned r = x.u + 0x7fffu + ((x.u >> 16) & 1u);   // RNE
    return (u16t)(r >> 16);
}
__device__ __forceinline__ float bf2f(u16t h) {
    return __uint_as_float(((unsigned)h) << 16);
}
__device__ __forceinline__ float celu_f(float x) {
    return x > 0.f ? x : 0.1f * (__expf(x * 10.f) - 1.f);
}
__device__ __forceinline__ void gll16(const void* g, void* l) {
    __builtin_amdgcn_global_load_lds(
        (const __attribute__((address_space(1))) void*)g,
        (__attribute__((address_space(3))) void*)l, 16, 0, 0);
}

// ---------------- prep kernels ----------------

// atom -> slot within its species block; wave-aggregated atomics
__global__ void assign_k(const int* __restrict__ sp, int* __restrict__ cnt,
                         int* __restrict__ src_of) {
    int i = blockIdx.x * 256 + threadIdx.x;
    int lane = threadIdx.x & 63;
    int s = (i < NATOMS) ? sp[i] : -1;
#pragma unroll
    for (int t = 0; t < SSP; ++t) {
        unsigned long long m = __ballot(s == t);
        if (s == t) {
            int leader = __ffsll((unsigned long long)m) - 1;
            int rank = __popcll(m & ((1ull << lane) - 1ull));
            int base = 0;
            if (lane == leader) base = atomicAdd(&cnt[t], __popcll(m));
            base = __shfl(base, leader);
            src_of[t * GPAD + base + rank] = i;
        }
    }
}

// species-sorted bf16 X [7][7296][1024]; one wave per row, 4 rows/block
__global__ void gather_k(const float* __restrict__ aev, const int* __restrict__ src_of,
                         u16t* __restrict__ X) {
    int wv = threadIdx.x >> 6, lane = threadIdx.x & 63;
    int s = blockIdx.y;
    int r = blockIdx.x * 4 + wv;                 // 0..7295
    int b = s * GPAD + r;
    bool valid = (r < GRP);
    int src = valid ? src_of[b] : 0;
    const float* ap = aev + (size_t)src * DIN;
    u16t* xp = X + (size_t)b * KP;
#pragma unroll
    for (int j = 0; j < 4; ++j) {
        int idx = j * 64 + lane;                 // 0..255
        int c = idx * 4;
        ushort4 o; o.x = 0; o.y = 0; o.z = 0; o.w = 0;
        if (valid && c < DIN) {
            float4 v = *(const float4*)(ap + c);
            o.x = f2bf(v.x); o.y = f2bf(v.y); o.z = f2bf(v.z); o.w = f2bf(v.w);
        }
        *(ushort4*)(xp + c) = o;
    }
}

// src [batch][K_in][C] fp32 -> dst [batch][C][K_out] bf16, zero-fill K_in..K_out
__global__ void transpose_convert_k(const float* __restrict__ src, u16t* __restrict__ dst,
                                    int K_in, int C, int K_out) {
    __shared__ float tile[64][65];
    int b = blockIdx.z;
    int k0 = blockIdx.x * 64, c0 = blockIdx.y * 64;
    int tx = threadIdx.x & 63, ty = threadIdx.x >> 6;
    const float* sp = src + (size_t)b * K_in * C;
#pragma unroll
    for (int i = 0; i < 16; ++i) {
        int kl = i * 4 + ty;
        int k = k0 + kl, c = c0 + tx;
        float v = (k < K_in && c < C) ? sp[(size_t)k * C + c] : 0.f;
        tile[kl][tx] = v;
    }
    __syncthreads();
    u16t* dp = dst + (size_t)b * C * K_out;
#pragma unroll
    for (int i = 0; i < 16; ++i) {
        int cl = i * 4 + ty;
        int c = c0 + cl, k = k0 + tx;
        if (c < C && k < K_out)
            dp[(size_t)c * K_out + k] = f2bf(tile[tx][cl]);
    }
}

// ---------------- layer 1: 2-phase pipelined GEMM, 2 models per block ----------
// grid (114 = 57 mtiles x 2 ntiles, GBSM/2), 256 threads (4 waves, 2x2)
// BK=32, double-buffered staging (2 x 24KB). Per K-step: ds_read frags from
// buf[cur], issue next tile's global_load_lds into buf[cur^1], MFMA, then ONE
// __syncthreads (vmcnt drain AFTER compute -> staging latency hidden).
__launch_bounds__(256, 2)
__global__ void gemm1(const u16t* __restrict__ X, const u16t* __restrict__ W0T,
                      const float* __restrict__ b0, u16t* __restrict__ H0, int bsm0) {
    __shared__ __attribute__((aligned(16))) char lds[49152]; // 2 x (A 8K + B0 8K + B1 8K)

    const int tid = threadIdx.x, w = tid >> 6, lane = tid & 63;
    const int l15 = lane & 15, quad = lane >> 4;
    const int mtile = blockIdx.x >> 1, ntile = blockIdx.x & 1;
    const int by = blockIdx.y;
    const int bsm = bsm0 + by * 2;               // model pair (bsm, bsm+1), same species
    const int s = bsm >> 3;
    const int wr = w & 1, wc = w >> 1;

    const u16t* Xp  = X + ((size_t)s * GPAD + (size_t)mtile * 128) * KP;
    const u16t* Wp0 = W0T + ((size_t)bsm * H0D + (size_t)ntile * 128) * KP;
    const u16t* Wp1 = W0T + ((size_t)(bsm + 1) * H0D + (size_t)ntile * 128) * KP;

    // staging map (BK=32): LDS chunk u (16B) <- global (r = u>>2, c = (u&3)^(r&3))
    const u16t* gA[2]; const u16t* gB0[2]; const u16t* gB1[2];
#pragma unroll
    for (int j = 0; j < 2; ++j) {
        int u = j * 256 + tid;
        int r = u >> 2;
        int cs = (u & 3) ^ (r & 3);
        size_t off = (size_t)r * KP + cs * 8;
        gA[j]  = Xp  + off;
        gB0[j] = Wp0 + off;
        gB1[j] = Wp1 + off;
    }
    // fragment LDS offsets within a buffer (row r: 64B; chunk = quad ^ (r&3))
    const int chv = (quad ^ (l15 & 3)) * 16;
    int aoff[4], boff[4];
#pragma unroll
    for (int t = 0; t < 4; ++t) {
        aoff[t] = (wr * 64 + t * 16 + l15) * 64 + chv;
        boff[t] = (wc * 64 + t * 16 + l15) * 64 + chv;
    }

    float4v acc[2][4][4];
#pragma unroll
    for (int m = 0; m < 2; ++m)
#pragma unroll
        for (int i = 0; i < 4; ++i)
#pragma unroll
            for (int j = 0; j < 4; ++j) acc[m][i][j] = (float4v){0.f, 0.f, 0.f, 0.f};

    // prologue: stage tile 0 into buf 0
    {
        char* base = lds;
#pragma unroll
        for (int j = 0; j < 2; ++j) {
            gll16(gA[j],  base + j * 4096 + w * 1024);
            gll16(gB0[j], base + 8192  + j * 4096 + w * 1024);
            gll16(gB1[j], base + 16384 + j * 4096 + w * 1024);
        }
    }
    __syncthreads();

    int cur = 0;
    for (int kt = 0; kt < 32; ++kt) {
        const char* bp = lds + cur * 24576;
        // 1) ds_read current fragments (before gll16 issue: no LDS alias stall)
        short8 a[4], b0f[4], b1f[4];
#pragma unroll
        for (int rt = 0; rt < 4; ++rt) a[rt] = *(const short8*)(bp + aoff[rt]);
#pragma unroll
        for (int ct = 0; ct < 4; ++ct) {
            b0f[ct] = *(const short8*)(bp + 8192  + boff[ct]);
            b1f[ct] = *(const short8*)(bp + 16384 + boff[ct]);
        }
        // 2) issue next tile's staging into the other buffer
        if (kt < 31) {
            char* base = lds + (cur ^ 1) * 24576;
            const int ko = (kt + 1) * 32;
#pragma unroll
            for (int j = 0; j < 2; ++j) {
                gll16(gA[j]  + ko, base + j * 4096 + w * 1024);
                gll16(gB0[j] + ko, base + 8192  + j * 4096 + w * 1024);
                gll16(gB1[j] + ko, base + 16384 + j * 4096 + w * 1024);
            }
        }
        // 3) MFMA on current fragments (waits lgkm only)
#pragma unroll
        for (int rt = 0; rt < 4; ++rt)
#pragma unroll
            for (int ct = 0; ct < 4; ++ct) {
                acc[0][rt][ct] = __builtin_amdgcn_mfma_f32_16x16x32_bf16(a[rt], b0f[ct], acc[0][rt][ct], 0, 0, 0);
                acc[1][rt][ct] = __builtin_amdgcn_mfma_f32_16x16x32_bf16(a[rt], b1f[ct], acc[1][rt][ct], 0, 0, 0);
            }
        // 4) one barrier per tile: drains vmcnt(0) AFTER compute
        __syncthreads();
        cur ^= 1;
    }

    // epilogue: bias + celu -> H0[slice][row][col] bf16 for both models
#pragma unroll
    for (int m = 0; m < 2; ++m) {
        float bias[4];
#pragma unroll
        for (int ct = 0; ct < 4; ++ct)
            bias[ct] = b0[(bsm + m) * H0D + ntile * 128 + wc * 64 + ct * 16 + l15];
        u16t* Hp = H0 + (size_t)(by * 2 + m) * GPAD * H0D;
#pragma unroll
        for (int rt = 0; rt < 4; ++rt)
#pragma unroll
            for (int ct = 0; ct < 4; ++ct) {
                int col = ntile * 128 + wc * 64 + ct * 16 + l15;
#pragma unroll
                for (int rg = 0; rg < 4; ++rg) {
                    int row = mtile * 128 + wr * 64 + rt * 16 + quad * 4 + rg;
                    Hp[(size_t)row * H0D + col] = f2bf(celu_f(acc[m][rt][ct][rg] + bias[ct]));
                }
            }
    }
}

// ---------------- layers 2-4 per 64-row tile ----------------
// grid (114, GBSM), 256 threads (4 waves: wr2 = w&1 rows, wc2 = w>>1 cols)
// LDS: single 32KB region, lH0 [64][256] then aliased as lH1 [64][192].
// Layer 4 computed straight from acc3 registers (no lH2, no LDS round-trip).
__launch_bounds__(256, 4)
__global__ void mlp234(const u16t* __restrict__ H0, const u16t* __restrict__ W1T,
                       const u16t* __restrict__ W2T, const float* __restrict__ W3,
                       const float* __restrict__ b1, const float* __restrict__ b2,
                       const float* __restrict__ b3, float* __restrict__ out, int bsm0) {
    __shared__ __attribute__((aligned(16))) char lbuf[32768]; // lH0, then lH1
    __shared__ float red[4];

    const int tid = threadIdx.x, w = tid >> 6, lane = tid & 63;
    const int l15 = lane & 15, quad = lane >> 4;
    const int by = blockIdx.y, bsm = bsm0 + by;
    const int g0 = blockIdx.x * 64;
    const int wr2 = w & 1, wc2 = w >> 1;

    // ---- stage H0 tile [64][256] via gll16; chunk u: r=u>>5, c'=u&31,
    //      src chunk c = (c'&24) | ((c'^r)&7)
    const u16t* Hg = H0 + ((size_t)by * GPAD + g0) * H0D;
#pragma unroll
    for (int j = 0; j < 8; ++j) {
        int u = j * 256 + w * 64 + lane;
        int r = u >> 5, c5 = u & 31;
        int cs = (c5 & 24) | ((c5 ^ r) & 7);
        gll16(Hg + (size_t)r * H0D + cs * 8, lbuf + j * 4096 + w * 1024);
    }

    // weight pointers (fragment-shaped, L2-hot); issue first W1 frags now so
    // their L2 latency overlaps the staging drain at the barrier.
    const u16t* W1p = W1T + (size_t)bsm * H1D * H0D;   // [192][256]
    const u16t* W2p = W2T + (size_t)bsm * H2D * H1D;   // [160][192]
    const u16t* bp1[6];
#pragma unroll
    for (int ct = 0; ct < 6; ++ct)
        bp1[ct] = W1p + (size_t)(wc2 * 96 + ct * 16 + l15) * H0D + quad * 8;
    short8 bc[6];
#pragma unroll
    for (int ct = 0; ct < 6; ++ct) bc[ct] = *(const short8*)(bp1[ct]);

    __syncthreads();                                   // H0 staged

    // ---- layer 2: C2[64 x 192] = H0 @ W1 ----
    float4v acc2[2][6];
#pragma unroll
    for (int i = 0; i < 2; ++i)
#pragma unroll
        for (int j = 0; j < 6; ++j) acc2[i][j] = (float4v){0.f, 0.f, 0.f, 0.f};

    for (int kc = 0; kc < 8; ++kc) {
        const int kn = ((kc + 1 < 8) ? kc + 1 : kc) * 32;
        short8 a[2];
#pragma unroll
        for (int rt = 0; rt < 2; ++rt) {
            int r = wr2 * 32 + rt * 16 + l15;
            int ch = kc * 4 + quad;
            int sw = (ch & 24) | ((ch ^ r) & 7);
            a[rt] = *(const short8*)(lbuf + r * 512 + sw * 16);
        }
        short8 bn[6];
#pragma unroll
        for (int ct = 0; ct < 6; ++ct) bn[ct] = *(const short8*)(bp1[ct] + kn);
#pragma unroll
        for (int rt = 0; rt < 2; ++rt)
#pragma unroll
            for (int ct = 0; ct < 6; ++ct)
                acc2[rt][ct] = __builtin_amdgcn_mfma_f32_16x16x32_bf16(a[rt], bc[ct], acc2[rt][ct], 0, 0, 0);
#pragma unroll
        for (int ct = 0; ct < 6; ++ct) bc[ct] = bn[ct];
    }

    // issue W2 fragment loads early (global, independent of LDS)
    const u16t* bp2[5];
#pragma unroll
    for (int ct = 0; ct < 5; ++ct)
        bp2[ct] = W2p + (size_t)(wc2 * 80 + ct * 16 + l15) * H1D + quad * 8;
    short8 bc3[5];
#pragma unroll
    for (int ct = 0; ct < 5; ++ct) bc3[ct] = *(const short8*)(bp2[ct]);

    __syncthreads();   // all lH0 reads complete before lH1 overwrites lbuf

    { // epilogue 2 -> lH1 [64][192] in lbuf, chunk swizzle low3
        float bias[6];
#pragma unroll
        for (int ct = 0; ct < 6; ++ct) bias[ct] = b1[bsm * H1D + wc2 * 96 + ct * 16 + l15];
#pragma unroll
        for (int rt = 0; rt < 2; ++rt)
#pragma unroll
            for (int ct = 0; ct < 6; ++ct) {
                int h = wc2 * 96 + ct * 16 + l15;
                int ch = h >> 3;
#pragma unroll
                for (int rg = 0; rg < 4; ++rg) {
                    int g = wr2 * 32 + rt * 16 + quad * 4 + rg;
                    float v = celu_f(acc2[rt][ct][rg] + bias[ct]);
                    int sw = (ch & ~7) | ((ch ^ g) & 7);
                    *(u16t*)(lbuf + g * 384 + sw * 16 + (h & 7) * 2) = f2bf(v);
                }
            }
    }
    __syncthreads();

    // ---- layer 3: C3[64 x 160] = H1 @ W2 ----
    float4v acc3[2][5];
#pragma unroll
    for (int i = 0; i < 2; ++i)
#pragma unroll
        for (int j = 0; j < 5; ++j) acc3[i][j] = (float4v){0.f, 0.f, 0.f, 0.f};

    for (int kc = 0; kc < 6; ++kc) {
        const int kn = ((kc + 1 < 6) ? kc + 1 : kc) * 32;
        short8 a[2];
#pragma unroll
        for (int rt = 0; rt < 2; ++rt) {
            int r = wr2 * 32 + rt * 16 + l15;
            int ch = kc * 4 + quad;
            int sw = (ch & ~7) | ((ch ^ r) & 7);
            a[rt] = *(const short8*)(lbuf + r * 384 + sw * 16);
        }
        short8 bn[5];
#pragma unroll
        for (int ct = 0; ct < 5; ++ct) bn[ct] = *(const short8*)(bp2[ct] + kn);
#pragma unroll
        for (int rt = 0; rt < 2; ++rt)
#pragma unroll
            for (int ct = 0; ct < 5; ++ct)
                acc3[rt][ct] = __builtin_amdgcn_mfma_f32_16x16x32_bf16(a[rt], bc3[ct], acc3[rt][ct], 0, 0, 0);
#pragma unroll
        for (int ct = 0; ct < 5; ++ct) bc3[ct] = bn[ct];
    }

    // ---- layer 4 straight from acc3: block energy sum, no LDS tile ----
    {
        float b2r[5], w3r[5];
#pragma unroll
        for (int ct = 0; ct < 5; ++ct) {
            int col = wc2 * 80 + ct * 16 + l15;
            b2r[ct] = b2[bsm * H2D + col];
            w3r[ct] = W3[bsm * H2D + col];
        }
        float s = 0.f;
#pragma unroll
        for (int rt = 0; rt < 2; ++rt)
#pragma unroll
            for (int rg = 0; rg < 4; ++rg) {
                int row = wr2 * 32 + rt * 16 + quad * 4 + rg;
                if (g0 + row < GRP) {
#pragma unroll
                    for (int ct = 0; ct < 5; ++ct)
                        s += celu_f(acc3[rt][ct][rg] + b2r[ct]) * w3r[ct];
                }
            }
#pragma unroll
        for (int off = 32; off; off >>= 1) s += __shfl_xor(s, off);
        if (lane == 0) red[w] = s;
    }
    __syncthreads();
    if (tid == 0) {
        int nv = GRP - g0; nv = nv < 0 ? 0 : (nv > 64 ? 64 : nv);
        atomicAdd(out, (red[0] + red[1] + red[2] + red[3] + (float)nv * b3[bsm]) * 0.125f);
    }
}

// ---------------- host launch ----------------
extern "C" void kernel_launch(void* const* d_in, const int* in_sizes, int n_in,
                              void* d_out, int out_size, void* d_ws, size_t ws_size,
                              hipStream_t stream) {
    const int*   species = (const int*)d_in[0];
    const float* aev     = (const float*)d_in[1];
    const float* W0      = (const float*)d_in[2];
    const float* b0      = (const float*)d_in[3];
    const float* W1      = (const float*)d_in[4];
    const float* b1      = (const float*)d_in[5];
    const float* W2      = (const float*)d_in[6];
    const float* b2      = (const float*)d_in[7];
    const float* W3      = (const float*)d_in[8];
    const float* b3      = (const float*)d_in[9];
    float* out = (float*)d_out;
    char*  ws  = (char*)d_ws;

    int*  cnt    = (int*)(ws + OFF_CNT);
    int*  src_of = (int*)(ws + OFF_SRC);
    u16t* X      = (u16t*)(ws + OFF_X);
    u16t* W0T    = (u16t*)(ws + OFF_W0T);
    u16t* W1T    = (u16t*)(ws + OFF_W1T);
    u16t* W2T    = (u16t*)(ws + OFF_W2T);
    u16t* H0     = (u16t*)(ws + OFF_H0);

    hipMemsetAsync(cnt, 0, 32, stream);
    hipMemsetAsync(d_out, 0, sizeof(float), stream);

    assign_k<<<(NATOMS + 255) / 256, 256, 0, stream>>>(species, cnt, src_of);
    gather_k<<<dim3(GPAD / 4, SSP), 256, 0, stream>>>(aev, src_of, X);
    transpose_convert_k<<<dim3(16, 4, 56), 256, 0, stream>>>(W0, W0T, DIN, H0D, KP);
    transpose_convert_k<<<dim3(4, 3, 56), 256, 0, stream>>>(W1, W1T, H0D, H1D, H0D);
    transpose_convert_k<<<dim3(3, 3, 56), 256, 0, stream>>>(W2, W2T, H1D, H2D, H1D);

    for (int p = 0; p < 2; ++p) {
        gemm1<<<dim3(114, GBSM / 2), 256, 0, stream>>>(X, W0T, b0, H0, p * GBSM);
        mlp234<<<dim3(114, GBSM), 256, 0, stream>>>(H0, W1T, W2T, W3,
                                                    b1, b2, b3, out, p * GBSM);
    }
}

// Round 6
// 814.324 us; speedup vs baseline: 1.2249x; 1.2249x over previous
//
#include <hip/hip_runtime.h>
#include <cstdint>
#include <cstddef>

typedef unsigned short u16t;
typedef __attribute__((ext_vector_type(8))) short short8;   // 8 x bf16 (4 VGPRs)
typedef __attribute__((ext_vector_type(4))) float float4v;  // MFMA C/D frag

#define NATOMS 50400
#define SSP    7
#define DIN    1008
#define KP     1024     // layer-1 K padded
#define GRP    7200     // atoms per species
#define GPAD   7296     // 57 * 128
#define H0D    256
#define H1D    192
#define H2D    160

// ---- workspace byte offsets (all 16B aligned) ----
#define OFF_CNT   0ull
#define OFF_SRC   256ull                 // 7*7296*4 = 204288
#define OFF_X     204544ull              // 7*7296*1024*2 = 104595456
#define OFF_W0T   104800000ull           // 56*256*1024*2 = 29360128
#define OFF_W1T   134160128ull           // 56*192*256*2  = 5505024
#define OFF_W2T   139665152ull           // 56*160*192*2  = 3440640 -> end 143105792

__device__ __forceinline__ u16t f2bf(float f) {
    union { float f; unsigned u; } x; x.f = f;
    unsigned r = x.u + 0x7fffu + ((x.u >> 16) & 1u);   // RNE
    return (u16t)(r >> 16);
}
__device__ __forceinline__ float bf2f(u16t h) {
    return __uint_as_float(((unsigned)h) << 16);
}
__device__ __forceinline__ float celu_f(float x) {
    return x > 0.f ? x : 0.1f * (__expf(x * 10.f) - 1.f);
}
__device__ __forceinline__ void gll16(const void* g, void* l) {
    __builtin_amdgcn_global_load_lds(
        (const __attribute__((address_space(1))) void*)g,
        (__attribute__((address_space(3))) void*)l, 16, 0, 0);
}

// ---------------- prep kernels ----------------

// atom -> slot within its species block; wave-aggregated atomics
__global__ void assign_k(const int* __restrict__ sp, int* __restrict__ cnt,
                         int* __restrict__ src_of) {
    int i = blockIdx.x * 256 + threadIdx.x;
    int lane = threadIdx.x & 63;
    int s = (i < NATOMS) ? sp[i] : -1;
#pragma unroll
    for (int t = 0; t < SSP; ++t) {
        unsigned long long m = __ballot(s == t);
        if (s == t) {
            int leader = __ffsll((unsigned long long)m) - 1;
            int rank = __popcll(m & ((1ull << lane) - 1ull));
            int base = 0;
            if (lane == leader) base = atomicAdd(&cnt[t], __popcll(m));
            base = __shfl(base, leader);
            src_of[t * GPAD + base + rank] = i;
        }
    }
}

// species-sorted bf16 X [7][7296][1024]; one wave per row, 4 rows/block
__global__ void gather_k(const float* __restrict__ aev, const int* __restrict__ src_of,
                         u16t* __restrict__ X) {
    int wv = threadIdx.x >> 6, lane = threadIdx.x & 63;
    int s = blockIdx.y;
    int r = blockIdx.x * 4 + wv;                 // 0..7295
    int b = s * GPAD + r;
    bool valid = (r < GRP);
    int src = valid ? src_of[b] : 0;
    const float* ap = aev + (size_t)src * DIN;
    u16t* xp = X + (size_t)b * KP;
#pragma unroll
    for (int j = 0; j < 4; ++j) {
        int idx = j * 64 + lane;                 // 0..255
        int c = idx * 4;
        ushort4 o; o.x = 0; o.y = 0; o.z = 0; o.w = 0;
        if (valid && c < DIN) {
            float4 v = *(const float4*)(ap + c);
            o.x = f2bf(v.x); o.y = f2bf(v.y); o.z = f2bf(v.z); o.w = f2bf(v.w);
        }
        *(ushort4*)(xp + c) = o;
    }
}

// src [batch][K_in][C] fp32 -> dst [batch][C][K_out] bf16, zero-fill K_in..K_out
__global__ void transpose_convert_k(const float* __restrict__ src, u16t* __restrict__ dst,
                                    int K_in, int C, int K_out) {
    __shared__ float tile[64][65];
    int b = blockIdx.z;
    int k0 = blockIdx.x * 64, c0 = blockIdx.y * 64;
    int tx = threadIdx.x & 63, ty = threadIdx.x >> 6;
    const float* sp = src + (size_t)b * K_in * C;
#pragma unroll
    for (int i = 0; i < 16; ++i) {
        int kl = i * 4 + ty;
        int k = k0 + kl, c = c0 + tx;
        float v = (k < K_in && c < C) ? sp[(size_t)k * C + c] : 0.f;
        tile[kl][tx] = v;
    }
    __syncthreads();
    u16t* dp = dst + (size_t)b * C * K_out;
#pragma unroll
    for (int i = 0; i < 16; ++i) {
        int cl = i * 4 + ty;
        int c = c0 + cl, k = k0 + tx;
        if (c < C && k < K_out)
            dp[(size_t)c * K_out + k] = f2bf(tile[tx][cl]);
    }
}

// ---------------- fully fused: layer1 GEMM + layers 2-4 ----------------
// grid (57 mtiles, 56 bsm), 256 threads (4 waves, 2x2: wr rows, wc cols).
// Per block: [128 rows x 256 cols] of H0 for ONE model, kept in acc[4][8]
// (same per-iter cost as the old 2-model/128-col block), then celu -> LDS
// tile, layers 2/3 via MFMA vs L2-hot W1T/W2T, layer 4 from registers.
// No H0 workspace round-trip, no second kernel, single pass over 56 bsm.
__launch_bounds__(256, 2)
__global__ void fused(const u16t* __restrict__ X, const u16t* __restrict__ W0T,
                      const u16t* __restrict__ W1T, const u16t* __restrict__ W2T,
                      const float* __restrict__ b0, const float* __restrict__ b1,
                      const float* __restrict__ b2, const float* __restrict__ b3,
                      const float* __restrict__ W3, float* __restrict__ out) {
    // staging phase: A [128][64] @0 (16K), B [256][64] @16384 (32K)
    // layers phase:  lH0 [128][512B] @0 (64K), then lH1 [128][384B] @0 (48K)
    __shared__ __attribute__((aligned(16))) char lbuf[65536];
    __shared__ float red[4];

    const int tid = threadIdx.x, w = tid >> 6, lane = tid & 63;
    const int l15 = lane & 15, quad = lane >> 4;
    const int mtile = blockIdx.x;                // 0..56
    const int bsm = blockIdx.y;                  // 0..55
    const int s = bsm >> 3;
    const int wr = w & 1, wc = w >> 1;

    const u16t* Xp = X + ((size_t)s * GPAD + (size_t)mtile * 128) * KP;
    const u16t* Wp = W0T + (size_t)bsm * H0D * KP;

    // staging maps: chunk u (16B) <- global (r = u>>3, c = (u&7) ^ (r&7))
    const u16t* gA[4]; const u16t* gB[8];
#pragma unroll
    for (int j = 0; j < 4; ++j) {
        int u = j * 256 + tid;
        int r = u >> 3, cs = (u & 7) ^ (r & 7);
        gA[j] = Xp + (size_t)r * KP + cs * 8;
    }
#pragma unroll
    for (int j = 0; j < 8; ++j) {
        int u = j * 256 + tid;
        int r = u >> 3, cs = (u & 7) ^ (r & 7);
        gB[j] = Wp + (size_t)r * KP + cs * 8;
    }
    // fragment LDS offsets (row stride 128B, XOR-8 chunk swizzle: conflict-free)
    int aoff[4][2], boff[8][2];
#pragma unroll
    for (int rt = 0; rt < 4; ++rt) {
        int r = wr * 64 + rt * 16 + l15;
#pragma unroll
        for (int ks = 0; ks < 2; ++ks)
            aoff[rt][ks] = r * 128 + (((ks * 4 + quad) ^ (r & 7)) * 16);
    }
#pragma unroll
    for (int ct = 0; ct < 8; ++ct) {
        int c = wc * 128 + ct * 16 + l15;
#pragma unroll
        for (int ks = 0; ks < 2; ++ks)
            boff[ct][ks] = c * 128 + (((ks * 4 + quad) ^ (c & 7)) * 16);
    }

    float4v acc[4][8];
#pragma unroll
    for (int i = 0; i < 4; ++i)
#pragma unroll
        for (int j = 0; j < 8; ++j) acc[i][j] = (float4v){0.f, 0.f, 0.f, 0.f};

    for (int kt = 0; kt < 16; ++kt) {
        const int ko = kt * 64;
        __syncthreads();                         // prev reads done
#pragma unroll
        for (int j = 0; j < 4; ++j) gll16(gA[j] + ko, lbuf + j * 4096 + w * 1024);
#pragma unroll
        for (int j = 0; j < 8; ++j) gll16(gB[j] + ko, lbuf + 16384 + j * 4096 + w * 1024);
        __syncthreads();                         // staging done
#pragma unroll
        for (int ks = 0; ks < 2; ++ks) {
            short8 a[4], b[8];
#pragma unroll
            for (int rt = 0; rt < 4; ++rt) a[rt] = *(const short8*)(lbuf + aoff[rt][ks]);
#pragma unroll
            for (int ct = 0; ct < 8; ++ct) b[ct] = *(const short8*)(lbuf + 16384 + boff[ct][ks]);
#pragma unroll
            for (int rt = 0; rt < 4; ++rt)
#pragma unroll
                for (int ct = 0; ct < 8; ++ct)
                    acc[rt][ct] = __builtin_amdgcn_mfma_f32_16x16x32_bf16(a[rt], b[ct], acc[rt][ct], 0, 0, 0);
        }
    }
    __syncthreads();   // all staging reads done before lH0 overwrites lbuf

    // ---- H0 tile -> LDS [128 rows][256 cols] bf16, chunk swizzle (c5&24)|((c5^r)&7)
    {
        float bias[8];
#pragma unroll
        for (int ct = 0; ct < 8; ++ct)
            bias[ct] = b0[bsm * H0D + wc * 128 + ct * 16 + l15];
#pragma unroll
        for (int rt = 0; rt < 4; ++rt)
#pragma unroll
            for (int ct = 0; ct < 8; ++ct) {
                int col = wc * 128 + ct * 16 + l15;
                int ch = col >> 3;
#pragma unroll
                for (int rg = 0; rg < 4; ++rg) {
                    int row = wr * 64 + rt * 16 + quad * 4 + rg;
                    int sw = (ch & 24) | ((ch ^ row) & 7);
                    *(u16t*)(lbuf + row * 512 + sw * 16 + (col & 7) * 2) =
                        f2bf(celu_f(acc[rt][ct][rg] + bias[ct]));
                }
            }
    }

    // weight pointers (fragment-shaped, L2-hot); issue first W1 frags pre-barrier
    const u16t* W1p = W1T + (size_t)bsm * H1D * H0D;   // [192][256]
    const u16t* W2p = W2T + (size_t)bsm * H2D * H1D;   // [160][192]
    const u16t* bp1[6];
#pragma unroll
    for (int ct = 0; ct < 6; ++ct)
        bp1[ct] = W1p + (size_t)(wc * 96 + ct * 16 + l15) * H0D + quad * 8;
    short8 bc[6];
#pragma unroll
    for (int ct = 0; ct < 6; ++ct) bc[ct] = *(const short8*)(bp1[ct]);

    __syncthreads();                                   // lH0 complete

    // ---- layer 2: C2[128 x 192] = H0 @ W1 ----
    float4v acc2[4][6];
#pragma unroll
    for (int i = 0; i < 4; ++i)
#pragma unroll
        for (int j = 0; j < 6; ++j) acc2[i][j] = (float4v){0.f, 0.f, 0.f, 0.f};

    for (int kc = 0; kc < 8; ++kc) {
        const int kn = ((kc + 1 < 8) ? kc + 1 : kc) * 32;
        short8 a[4];
#pragma unroll
        for (int rt = 0; rt < 4; ++rt) {
            int r = wr * 64 + rt * 16 + l15;
            int ch = kc * 4 + quad;
            int sw = (ch & 24) | ((ch ^ r) & 7);
            a[rt] = *(const short8*)(lbuf + r * 512 + sw * 16);
        }
        short8 bn[6];
#pragma unroll
        for (int ct = 0; ct < 6; ++ct) bn[ct] = *(const short8*)(bp1[ct] + kn);
#pragma unroll
        for (int rt = 0; rt < 4; ++rt)
#pragma unroll
            for (int ct = 0; ct < 6; ++ct)
                acc2[rt][ct] = __builtin_amdgcn_mfma_f32_16x16x32_bf16(a[rt], bc[ct], acc2[rt][ct], 0, 0, 0);
#pragma unroll
        for (int ct = 0; ct < 6; ++ct) bc[ct] = bn[ct];
    }

    // issue W2 fragment loads early (global, independent of LDS)
    const u16t* bp2[5];
#pragma unroll
    for (int ct = 0; ct < 5; ++ct)
        bp2[ct] = W2p + (size_t)(wc * 80 + ct * 16 + l15) * H1D + quad * 8;
    short8 bc3[5];
#pragma unroll
    for (int ct = 0; ct < 5; ++ct) bc3[ct] = *(const short8*)(bp2[ct]);

    __syncthreads();   // all lH0 reads complete before lH1 overwrites lbuf

    { // epilogue 2 -> lH1 [128][192] bf16, chunk swizzle low3
        float bias[6];
#pragma unroll
        for (int ct = 0; ct < 6; ++ct) bias[ct] = b1[bsm * H1D + wc * 96 + ct * 16 + l15];
#pragma unroll
        for (int rt = 0; rt < 4; ++rt)
#pragma unroll
            for (int ct = 0; ct < 6; ++ct) {
                int h = wc * 96 + ct * 16 + l15;
                int ch = h >> 3;
#pragma unroll
                for (int rg = 0; rg < 4; ++rg) {
                    int g = wr * 64 + rt * 16 + quad * 4 + rg;
                    float v = celu_f(acc2[rt][ct][rg] + bias[ct]);
                    int sw = (ch & ~7) | ((ch ^ g) & 7);
                    *(u16t*)(lbuf + g * 384 + sw * 16 + (h & 7) * 2) = f2bf(v);
                }
            }
    }
    __syncthreads();

    // ---- layer 3: C3[128 x 160] = H1 @ W2 ----
    float4v acc3[4][5];
#pragma unroll
    for (int i = 0; i < 4; ++i)
#pragma unroll
        for (int j = 0; j < 5; ++j) acc3[i][j] = (float4v){0.f, 0.f, 0.f, 0.f};

    for (int kc = 0; kc < 6; ++kc) {
        const int kn = ((kc + 1 < 6) ? kc + 1 : kc) * 32;
        short8 a[4];
#pragma unroll
        for (int rt = 0; rt < 4; ++rt) {
            int r = wr * 64 + rt * 16 + l15;
            int ch = kc * 4 + quad;
            int sw = (ch & ~7) | ((ch ^ r) & 7);
            a[rt] = *(const short8*)(lbuf + r * 384 + sw * 16);
        }
        short8 bn[5];
#pragma unroll
        for (int ct = 0; ct < 5; ++ct) bn[ct] = *(const short8*)(bp2[ct] + kn);
#pragma unroll
        for (int rt = 0; rt < 4; ++rt)
#pragma unroll
            for (int ct = 0; ct < 5; ++ct)
                acc3[rt][ct] = __builtin_amdgcn_mfma_f32_16x16x32_bf16(a[rt], bc3[ct], acc3[rt][ct], 0, 0, 0);
#pragma unroll
        for (int ct = 0; ct < 5; ++ct) bc3[ct] = bn[ct];
    }

    // ---- layer 4 straight from acc3: block energy sum ----
    {
        float b2r[5], w3r[5];
#pragma unroll
        for (int ct = 0; ct < 5; ++ct) {
            int col = wc * 80 + ct * 16 + l15;
            b2r[ct] = b2[bsm * H2D + col];
            w3r[ct] = W3[bsm * H2D + col];
        }
        float sum = 0.f;
#pragma unroll
        for (int rt = 0; rt < 4; ++rt)
#pragma unroll
            for (int rg = 0; rg < 4; ++rg) {
                int row = mtile * 128 + wr * 64 + rt * 16 + quad * 4 + rg;
                if (row < GRP) {
#pragma unroll
                    for (int ct = 0; ct < 5; ++ct)
                        sum += celu_f(acc3[rt][ct][rg] + b2r[ct]) * w3r[ct];
                }
            }
#pragma unroll
        for (int off = 32; off; off >>= 1) sum += __shfl_xor(sum, off);
        if (lane == 0) red[w] = sum;
    }
    __syncthreads();
    if (tid == 0) {
        int nv = GRP - mtile * 128; nv = nv < 0 ? 0 : (nv > 128 ? 128 : nv);
        atomicAdd(out, (red[0] + red[1] + red[2] + red[3] + (float)nv * b3[bsm]) * 0.125f);
    }
}

// ---------------- host launch ----------------
extern "C" void kernel_launch(void* const* d_in, const int* in_sizes, int n_in,
                              void* d_out, int out_size, void* d_ws, size_t ws_size,
                              hipStream_t stream) {
    const int*   species = (const int*)d_in[0];
    const float* aev     = (const float*)d_in[1];
    const float* W0      = (const float*)d_in[2];
    const float* b0      = (const float*)d_in[3];
    const float* W1      = (const float*)d_in[4];
    const float* b1      = (const float*)d_in[5];
    const float* W2      = (const float*)d_in[6];
    const float* b2      = (const float*)d_in[7];
    const float* W3      = (const float*)d_in[8];
    const float* b3      = (const float*)d_in[9];
    float* out = (float*)d_out;
    char*  ws  = (char*)d_ws;

    int*  cnt    = (int*)(ws + OFF_CNT);
    int*  src_of = (int*)(ws + OFF_SRC);
    u16t* X      = (u16t*)(ws + OFF_X);
    u16t* W0T    = (u16t*)(ws + OFF_W0T);
    u16t* W1T    = (u16t*)(ws + OFF_W1T);
    u16t* W2T    = (u16t*)(ws + OFF_W2T);

    hipMemsetAsync(cnt, 0, 32, stream);
    hipMemsetAsync(d_out, 0, sizeof(float), stream);

    assign_k<<<(NATOMS + 255) / 256, 256, 0, stream>>>(species, cnt, src_of);
    gather_k<<<dim3(GPAD / 4, SSP), 256, 0, stream>>>(aev, src_of, X);
    transpose_convert_k<<<dim3(16, 4, 56), 256, 0, stream>>>(W0, W0T, DIN, H0D, KP);
    transpose_convert_k<<<dim3(4, 3, 56), 256, 0, stream>>>(W1, W1T, H0D, H1D, H0D);
    transpose_convert_k<<<dim3(3, 3, 56), 256, 0, stream>>>(W2, W2T, H1D, H2D, H1D);

    fused<<<dim3(GPAD / 128, 56), 256, 0, stream>>>(X, W0T, W1T, W2T,
                                                    b0, b1, b2, b3, W3, out);
}

// Round 7
// 796.722 us; speedup vs baseline: 1.2520x; 1.0221x over previous
//
#include <hip/hip_runtime.h>
#include <cstdint>
#include <cstddef>

typedef unsigned short u16t;
typedef __attribute__((ext_vector_type(8))) short short8;   // 8 x bf16 (4 VGPRs)
typedef __attribute__((ext_vector_type(4))) float float4v;  // MFMA C/D frag

#define NATOMS 50400
#define SSP    7
#define DIN    1008
#define KP     1024     // layer-1 K padded
#define GRP    7200     // atoms per species
#define GPAD   7296     // 57 * 128
#define H0D    256
#define H1D    192
#define H2D    160

// ---- workspace byte offsets (all 16B aligned) ----
#define OFF_CNT   0ull
#define OFF_SRC   256ull                 // 7*7296*4 = 204288
#define OFF_X     204544ull              // 7*7296*1024*2 = 104595456
#define OFF_W0T   104800000ull           // 56*256*1024*2 = 29360128
#define OFF_W1T   134160128ull           // 56*192*256*2  = 5505024
#define OFF_W2T   139665152ull           // 56*160*192*2  = 3440640 -> end 143105792

__device__ __forceinline__ u16t f2bf(float f) {
    union { float f; unsigned u; } x; x.f = f;
    unsigned r = x.u + 0x7fffu + ((x.u >> 16) & 1u);   // RNE
    return (u16t)(r >> 16);
}
__device__ __forceinline__ float bf2f(u16t h) {
    return __uint_as_float(((unsigned)h) << 16);
}
__device__ __forceinline__ float celu_f(float x) {
    return x > 0.f ? x : 0.1f * (__expf(x * 10.f) - 1.f);
}
__device__ __forceinline__ void gll16(const void* g, void* l) {
    __builtin_amdgcn_global_load_lds(
        (const __attribute__((address_space(1))) void*)g,
        (__attribute__((address_space(3))) void*)l, 16, 0, 0);
}

// ---------------- prep kernels ----------------

// atom -> slot within its species block; wave-aggregated atomics
__global__ void assign_k(const int* __restrict__ sp, int* __restrict__ cnt,
                         int* __restrict__ src_of) {
    int i = blockIdx.x * 256 + threadIdx.x;
    int lane = threadIdx.x & 63;
    int s = (i < NATOMS) ? sp[i] : -1;
#pragma unroll
    for (int t = 0; t < SSP; ++t) {
        unsigned long long m = __ballot(s == t);
        if (s == t) {
            int leader = __ffsll((unsigned long long)m) - 1;
            int rank = __popcll(m & ((1ull << lane) - 1ull));
            int base = 0;
            if (lane == leader) base = atomicAdd(&cnt[t], __popcll(m));
            base = __shfl(base, leader);
            src_of[t * GPAD + base + rank] = i;
        }
    }
}

// species-sorted bf16 X [7][7296][1024]; one wave per row, 4 rows/block.
// Vectorized: per lane 2 iters of (2x float4 load -> short8 16B store).
__global__ void gather_k(const float* __restrict__ aev, const int* __restrict__ src_of,
                         u16t* __restrict__ X) {
    int wv = threadIdx.x >> 6, lane = threadIdx.x & 63;
    int s = blockIdx.y;
    int r = blockIdx.x * 4 + wv;                 // 0..7295
    int b = s * GPAD + r;
    bool valid = (r < GRP);
    int src = valid ? src_of[b] : 0;
    const float* ap = aev + (size_t)src * DIN;
    u16t* xp = X + (size_t)b * KP;
#pragma unroll
    for (int j = 0; j < 2; ++j) {
        int c = (j * 64 + lane) * 8;             // 0..1016, step 8
        short8 o = (short8){0, 0, 0, 0, 0, 0, 0, 0};
        if (valid && c < DIN) {                  // DIN % 8 == 0: no partial chunk
            float4 v0 = *(const float4*)(ap + c);
            float4 v1 = *(const float4*)(ap + c + 4);
            o[0] = (short)f2bf(v0.x); o[1] = (short)f2bf(v0.y);
            o[2] = (short)f2bf(v0.z); o[3] = (short)f2bf(v0.w);
            o[4] = (short)f2bf(v1.x); o[5] = (short)f2bf(v1.y);
            o[6] = (short)f2bf(v1.z); o[7] = (short)f2bf(v1.w);
        }
        *(short8*)(xp + c) = o;
    }
}

// src [batch][K_in][C] fp32 -> dst [batch][C][K_out] bf16, zero-fill K_in..K_out.
// Store phase vectorized: each thread writes ushort4 (4 consecutive k) per pass.
__global__ void transpose_convert_k(const float* __restrict__ src, u16t* __restrict__ dst,
                                    int K_in, int C, int K_out) {
    __shared__ float tile[64][65];
    int b = blockIdx.z;
    int k0 = blockIdx.x * 64, c0 = blockIdx.y * 64;
    int tx = threadIdx.x & 63, ty = threadIdx.x >> 6;
    const float* sp = src + (size_t)b * K_in * C;
#pragma unroll
    for (int i = 0; i < 16; ++i) {
        int kl = i * 4 + ty;
        int k = k0 + kl, c = c0 + tx;
        float v = (k < K_in && c < C) ? sp[(size_t)k * C + c] : 0.f;
        tile[kl][tx] = v;
    }
    __syncthreads();
    u16t* dp = dst + (size_t)b * C * K_out;
    int kq = (threadIdx.x & 15) * 4;             // 0..60, step 4
    int cb = threadIdx.x >> 4;                   // 0..15
#pragma unroll
    for (int p = 0; p < 4; ++p) {
        int cl = p * 16 + cb;
        int c = c0 + cl;
        if (c < C) {
            ushort4 o;
            o.x = f2bf(tile[kq + 0][cl]); o.y = f2bf(tile[kq + 1][cl]);
            o.z = f2bf(tile[kq + 2][cl]); o.w = f2bf(tile[kq + 3][cl]);
            *(ushort4*)(dp + (size_t)c * K_out + k0 + kq) = o;
        }
    }
}

// ---------------- fully fused: layer1 GEMM + layers 2-4 ----------------
// grid (57 mtiles, 56 bsm), 256 threads (4 waves, 2x2: wr rows, wc cols).
// Per block: [128 rows x 256 cols] of H0 for ONE model, kept in acc[4][8],
// then celu -> LDS tile, layers 2/3 via MFMA vs L2-hot W1T/W2T, layer 4
// from registers. No H0 round-trip, single pass over 56 bsm.
__launch_bounds__(256, 2)
__global__ void fused(const u16t* __restrict__ X, const u16t* __restrict__ W0T,
                      const u16t* __restrict__ W1T, const u16t* __restrict__ W2T,
                      const float* __restrict__ b0, const float* __restrict__ b1,
                      const float* __restrict__ b2, const float* __restrict__ b3,
                      const float* __restrict__ W3, float* __restrict__ out) {
    // staging phase: A [128][64] @0 (16K), B [256][64] @16384 (32K)
    // layers phase:  lH0 [128][512B] @0 (64K), then lH1 [128][384B] @0 (48K)
    __shared__ __attribute__((aligned(16))) char lbuf[65536];
    __shared__ float red[4];

    const int tid = threadIdx.x, w = tid >> 6, lane = tid & 63;
    const int l15 = lane & 15, quad = lane >> 4;
    const int mtile = blockIdx.x;                // 0..56
    const int bsm = blockIdx.y;                  // 0..55
    const int s = bsm >> 3;
    const int wr = w & 1, wc = w >> 1;

    const u16t* Xp = X + ((size_t)s * GPAD + (size_t)mtile * 128) * KP;
    const u16t* Wp = W0T + (size_t)bsm * H0D * KP;

    // staging maps: chunk u (16B) <- global (r = u>>3, c = (u&7) ^ (r&7))
    const u16t* gA[4]; const u16t* gB[8];
#pragma unroll
    for (int j = 0; j < 4; ++j) {
        int u = j * 256 + tid;
        int r = u >> 3, cs = (u & 7) ^ (r & 7);
        gA[j] = Xp + (size_t)r * KP + cs * 8;
    }
#pragma unroll
    for (int j = 0; j < 8; ++j) {
        int u = j * 256 + tid;
        int r = u >> 3, cs = (u & 7) ^ (r & 7);
        gB[j] = Wp + (size_t)r * KP + cs * 8;
    }
    // fragment LDS offsets (row stride 128B, XOR-8 chunk swizzle: conflict-free)
    int aoff[4][2], boff[8][2];
#pragma unroll
    for (int rt = 0; rt < 4; ++rt) {
        int r = wr * 64 + rt * 16 + l15;
#pragma unroll
        for (int ks = 0; ks < 2; ++ks)
            aoff[rt][ks] = r * 128 + (((ks * 4 + quad) ^ (r & 7)) * 16);
    }
#pragma unroll
    for (int ct = 0; ct < 8; ++ct) {
        int c = wc * 128 + ct * 16 + l15;
#pragma unroll
        for (int ks = 0; ks < 2; ++ks)
            boff[ct][ks] = c * 128 + (((ks * 4 + quad) ^ (c & 7)) * 16);
    }

    float4v acc[4][8];
#pragma unroll
    for (int i = 0; i < 4; ++i)
#pragma unroll
        for (int j = 0; j < 8; ++j) acc[i][j] = (float4v){0.f, 0.f, 0.f, 0.f};

    for (int kt = 0; kt < 16; ++kt) {
        const int ko = kt * 64;
        __syncthreads();                         // prev reads done
#pragma unroll
        for (int j = 0; j < 4; ++j) gll16(gA[j] + ko, lbuf + j * 4096 + w * 1024);
#pragma unroll
        for (int j = 0; j < 8; ++j) gll16(gB[j] + ko, lbuf + 16384 + j * 4096 + w * 1024);
        __syncthreads();                         // staging done
#pragma unroll
        for (int ks = 0; ks < 2; ++ks) {
            short8 a[4], b[8];
#pragma unroll
            for (int rt = 0; rt < 4; ++rt) a[rt] = *(const short8*)(lbuf + aoff[rt][ks]);
#pragma unroll
            for (int ct = 0; ct < 8; ++ct) b[ct] = *(const short8*)(lbuf + 16384 + boff[ct][ks]);
#pragma unroll
            for (int rt = 0; rt < 4; ++rt)
#pragma unroll
                for (int ct = 0; ct < 8; ++ct)
                    acc[rt][ct] = __builtin_amdgcn_mfma_f32_16x16x32_bf16(a[rt], b[ct], acc[rt][ct], 0, 0, 0);
        }
    }
    __syncthreads();   // all staging reads done before lH0 overwrites lbuf

    // ---- H0 tile -> LDS [128 rows][256 cols] bf16, chunk swizzle (c5&24)|((c5^r)&7)
    {
        float bias[8];
#pragma unroll
        for (int ct = 0; ct < 8; ++ct)
            bias[ct] = b0[bsm * H0D + wc * 128 + ct * 16 + l15];
#pragma unroll
        for (int rt = 0; rt < 4; ++rt)
#pragma unroll
            for (int ct = 0; ct < 8; ++ct) {
                int col = wc * 128 + ct * 16 + l15;
                int ch = col >> 3;
#pragma unroll
                for (int rg = 0; rg < 4; ++rg) {
                    int row = wr * 64 + rt * 16 + quad * 4 + rg;
                    int sw = (ch & 24) | ((ch ^ row) & 7);
                    *(u16t*)(lbuf + row * 512 + sw * 16 + (col & 7) * 2) =
                        f2bf(celu_f(acc[rt][ct][rg] + bias[ct]));
                }
            }
    }

    // weight pointers (fragment-shaped, L2-hot); issue first W1 frags pre-barrier
    const u16t* W1p = W1T + (size_t)bsm * H1D * H0D;   // [192][256]
    const u16t* W2p = W2T + (size_t)bsm * H2D * H1D;   // [160][192]
    const u16t* bp1[6];
#pragma unroll
    for (int ct = 0; ct < 6; ++ct)
        bp1[ct] = W1p + (size_t)(wc * 96 + ct * 16 + l15) * H0D + quad * 8;
    short8 bc[6];
#pragma unroll
    for (int ct = 0; ct < 6; ++ct) bc[ct] = *(const short8*)(bp1[ct]);

    __syncthreads();                                   // lH0 complete

    // ---- layer 2: C2[128 x 192] = H0 @ W1 ----
    float4v acc2[4][6];
#pragma unroll
    for (int i = 0; i < 4; ++i)
#pragma unroll
        for (int j = 0; j < 6; ++j) acc2[i][j] = (float4v){0.f, 0.f, 0.f, 0.f};

    for (int kc = 0; kc < 8; ++kc) {
        const int kn = ((kc + 1 < 8) ? kc + 1 : kc) * 32;
        short8 a[4];
#pragma unroll
        for (int rt = 0; rt < 4; ++rt) {
            int r = wr * 64 + rt * 16 + l15;
            int ch = kc * 4 + quad;
            int sw = (ch & 24) | ((ch ^ r) & 7);
            a[rt] = *(const short8*)(lbuf + r * 512 + sw * 16);
        }
        short8 bn[6];
#pragma unroll
        for (int ct = 0; ct < 6; ++ct) bn[ct] = *(const short8*)(bp1[ct] + kn);
#pragma unroll
        for (int rt = 0; rt < 4; ++rt)
#pragma unroll
            for (int ct = 0; ct < 6; ++ct)
                acc2[rt][ct] = __builtin_amdgcn_mfma_f32_16x16x32_bf16(a[rt], bc[ct], acc2[rt][ct], 0, 0, 0);
#pragma unroll
        for (int ct = 0; ct < 6; ++ct) bc[ct] = bn[ct];
    }

    // issue W2 fragment loads early (global, independent of LDS)
    const u16t* bp2[5];
#pragma unroll
    for (int ct = 0; ct < 5; ++ct)
        bp2[ct] = W2p + (size_t)(wc * 80 + ct * 16 + l15) * H1D + quad * 8;
    short8 bc3[5];
#pragma unroll
    for (int ct = 0; ct < 5; ++ct) bc3[ct] = *(const short8*)(bp2[ct]);

    __syncthreads();   // all lH0 reads complete before lH1 overwrites lbuf

    { // epilogue 2 -> lH1 [128][192] bf16, chunk swizzle low3
        float bias[6];
#pragma unroll
        for (int ct = 0; ct < 6; ++ct) bias[ct] = b1[bsm * H1D + wc * 96 + ct * 16 + l15];
#pragma unroll
        for (int rt = 0; rt < 4; ++rt)
#pragma unroll
            for (int ct = 0; ct < 6; ++ct) {
                int h = wc * 96 + ct * 16 + l15;
                int ch = h >> 3;
#pragma unroll
                for (int rg = 0; rg < 4; ++rg) {
                    int g = wr * 64 + rt * 16 + quad * 4 + rg;
                    float v = celu_f(acc2[rt][ct][rg] + bias[ct]);
                    int sw = (ch & ~7) | ((ch ^ g) & 7);
                    *(u16t*)(lbuf + g * 384 + sw * 16 + (h & 7) * 2) = f2bf(v);
                }
            }
    }
    __syncthreads();

    // ---- layer 3: C3[128 x 160] = H1 @ W2 ----
    float4v acc3[4][5];
#pragma unroll
    for (int i = 0; i < 4; ++i)
#pragma unroll
        for (int j = 0; j < 5; ++j) acc3[i][j] = (float4v){0.f, 0.f, 0.f, 0.f};

    for (int kc = 0; kc < 6; ++kc) {
        const int kn = ((kc + 1 < 6) ? kc + 1 : kc) * 32;
        short8 a[4];
#pragma unroll
        for (int rt = 0; rt < 4; ++rt) {
            int r = wr * 64 + rt * 16 + l15;
            int ch = kc * 4 + quad;
            int sw = (ch & ~7) | ((ch ^ r) & 7);
            a[rt] = *(const short8*)(lbuf + r * 384 + sw * 16);
        }
        short8 bn[5];
#pragma unroll
        for (int ct = 0; ct < 5; ++ct) bn[ct] = *(const short8*)(bp2[ct] + kn);
#pragma unroll
        for (int rt = 0; rt < 4; ++rt)
#pragma unroll
            for (int ct = 0; ct < 5; ++ct)
                acc3[rt][ct] = __builtin_amdgcn_mfma_f32_16x16x32_bf16(a[rt], bc3[ct], acc3[rt][ct], 0, 0, 0);
#pragma unroll
        for (int ct = 0; ct < 5; ++ct) bc3[ct] = bn[ct];
    }

    // ---- layer 4 straight from acc3: block energy sum ----
    {
        float b2r[5], w3r[5];
#pragma unroll
        for (int ct = 0; ct < 5; ++ct) {
            int col = wc * 80 + ct * 16 + l15;
            b2r[ct] = b2[bsm * H2D + col];
            w3r[ct] = W3[bsm * H2D + col];
        }
        float sum = 0.f;
#pragma unroll
        for (int rt = 0; rt < 4; ++rt)
#pragma unroll
            for (int rg = 0; rg < 4; ++rg) {
                int row = mtile * 128 + wr * 64 + rt * 16 + quad * 4 + rg;
                if (row < GRP) {
#pragma unroll
                    for (int ct = 0; ct < 5; ++ct)
                        sum += celu_f(acc3[rt][ct][rg] + b2r[ct]) * w3r[ct];
                }
            }
#pragma unroll
        for (int off = 32; off; off >>= 1) sum += __shfl_xor(sum, off);
        if (lane == 0) red[w] = sum;
    }
    __syncthreads();
    if (tid == 0) {
        int nv = GRP - mtile * 128; nv = nv < 0 ? 0 : (nv > 128 ? 128 : nv);
        atomicAdd(out, (red[0] + red[1] + red[2] + red[3] + (float)nv * b3[bsm]) * 0.125f);
    }
}

// ---------------- host launch ----------------
extern "C" void kernel_launch(void* const* d_in, const int* in_sizes, int n_in,
                              void* d_out, int out_size, void* d_ws, size_t ws_size,
                              hipStream_t stream) {
    const int*   species = (const int*)d_in[0];
    const float* aev     = (const float*)d_in[1];
    const float* W0      = (const float*)d_in[2];
    const float* b0      = (const float*)d_in[3];
    const float* W1      = (const float*)d_in[4];
    const float* b1      = (const float*)d_in[5];
    const float* W2      = (const float*)d_in[6];
    const float* b2      = (const float*)d_in[7];
    const float* W3      = (const float*)d_in[8];
    const float* b3      = (const float*)d_in[9];
    float* out = (float*)d_out;
    char*  ws  = (char*)d_ws;

    int*  cnt    = (int*)(ws + OFF_CNT);
    int*  src_of = (int*)(ws + OFF_SRC);
    u16t* X      = (u16t*)(ws + OFF_X);
    u16t* W0T    = (u16t*)(ws + OFF_W0T);
    u16t* W1T    = (u16t*)(ws + OFF_W1T);
    u16t* W2T    = (u16t*)(ws + OFF_W2T);

    hipMemsetAsync(cnt, 0, 32, stream);
    hipMemsetAsync(d_out, 0, sizeof(float), stream);

    assign_k<<<(NATOMS + 255) / 256, 256, 0, stream>>>(species, cnt, src_of);
    gather_k<<<dim3(GPAD / 4, SSP), 256, 0, stream>>>(aev, src_of, X);
    transpose_convert_k<<<dim3(16, 4, 56), 256, 0, stream>>>(W0, W0T, DIN, H0D, KP);
    transpose_convert_k<<<dim3(4, 3, 56), 256, 0, stream>>>(W1, W1T, H0D, H1D, H0D);
    transpose_convert_k<<<dim3(3, 3, 56), 256, 0, stream>>>(W2, W2T, H1D, H2D, H1D);

    fused<<<dim3(GPAD / 128, 56), 256, 0, stream>>>(X, W0T, W1T, W2T,
                                                    b0, b1, b2, b3, W3, out);
}